// Round 6
// baseline (29082.071 us; speedup 1.0000x reference)
//
#include <hip/hip_runtime.h>
#include <cfloat>
#include <cmath>

#define Bn 128
#define Tn 512
#define En 256
#define Hn 512
#define NTAGS 32
#define LDW 132                  // padded LDS row stride
#define WPAD 20                  // padded W row stride

// ws float offsets
#define OFF_HF 0                          // [2][512][128] fwd h ([k][b])
#define OFF_HB 131072                     // [2][512][128] bwd h
#define OFF_BAR 262144                    // 1024 floats barrier area
#define OFF_EF 263168                     // [512][32][128] emissions fwd
#define OFF_EB (OFF_EF + Tn * NTAGS * Bn) // 2360320
// end: 4457472 floats = 17.0 MB

__device__ __forceinline__ void gridbar(unsigned* bar, int blk, int tid, unsigned target) {
  __syncthreads();
  if (tid == 0) {
    __threadfence();
    unsigned* phase = bar;                 // each on its own 128B line
    unsigned* root  = bar + 32;
    unsigned* gcnt  = bar + 64 + ((blk >> 4) << 5);
    unsigned o = __hip_atomic_fetch_add(gcnt, 1u, __ATOMIC_ACQ_REL, __HIP_MEMORY_SCOPE_AGENT);
    if (o == 15u) {
      __hip_atomic_store(gcnt, 0u, __ATOMIC_RELAXED, __HIP_MEMORY_SCOPE_AGENT);
      unsigned r = __hip_atomic_fetch_add(root, 1u, __ATOMIC_ACQ_REL, __HIP_MEMORY_SCOPE_AGENT);
      if (r == 15u) {
        __hip_atomic_store(root, 0u, __ATOMIC_RELAXED, __HIP_MEMORY_SCOPE_AGENT);
        __hip_atomic_fetch_add(phase, 1u, __ATOMIC_RELEASE, __HIP_MEMORY_SCOPE_AGENT);
      }
    }
    while (__hip_atomic_load(phase, __ATOMIC_ACQUIRE, __HIP_MEMORY_SCOPE_AGENT) < target)
      __builtin_amdgcn_s_sleep(2);
  }
  __syncthreads();
}

__global__ __launch_bounds__(512, 2) void lstm_persist_k(
    const float* __restrict__ X, const float* __restrict__ masks,
    const float* __restrict__ Wih_f, const float* __restrict__ Whh_f, const float* __restrict__ bias_f,
    const float* __restrict__ Wih_b, const float* __restrict__ Whh_b, const float* __restrict__ bias_b,
    const float* __restrict__ Wout, float* __restrict__ ws)
{
  __shared__ __align__(16) float WT[768 * WPAD];    // 61.4 KB  W [k][c]: rows 0..511 Whh, 512..767 Wih
  __shared__ __align__(16) float HX[2][64 * LDW];   // 67.6 KB  A chunks [k][b]
  __shared__ __align__(16) float GL[Bn * 17];       // 8.7 KB   gates
  __shared__ __align__(16) float WoL[512];          // 2 KB     Wout row (block's tag/dir)
  __shared__ __align__(16) float RS[16 * 32];       // 2 KB     emission partials

  const int tid   = threadIdx.x;
  const int blk   = blockIdx.x;
  const int lane  = tid & 63;
  const int wid   = __builtin_amdgcn_readfirstlane(tid >> 6);
  const int cg    = wid & 1;
  const int kt    = wid >> 1;
  const int bg    = lane & 31;
  const int khalf = lane >> 5;

  const int dir = blk >> 7;
  const int bbk = blk & 127;
  const float* Wih  = dir ? Wih_b  : Wih_f;
  const float* Whh  = dir ? Whh_b  : Whh_f;
  const float* bias = dir ? bias_b : bias_f;
  float* hbuf = ws + (dir ? OFF_HB : OFF_HF);
  float* Edst = ws + (dir ? OFF_EB : OFF_EF);
  unsigned* bar = (unsigned*)(ws + OFF_BAR);
  const int hidx0 = bbk * 4;
  const int etag = bbk & 31;
  const int ebq  = bbk >> 5;

  // ---- stage W once ----
  {
    const int lc = tid & 15;
    const int kw = tid >> 4;
    const int row = (lc >> 2) * Hn + hidx0 + (lc & 3);
    #pragma unroll
    for (int i = 0; i < 6; ++i) {
      const int k = (kw + i * 32) * 4;
      float4 w4;
      if (k < Hn) w4 = *(const float4*)&Whh[(size_t)row * Hn + k];
      else        w4 = *(const float4*)&Wih[(size_t)row * En + (k - Hn)];
      WT[(k + 0) * WPAD + lc] = w4.x; WT[(k + 1) * WPAD + lc] = w4.y;
      WT[(k + 2) * WPAD + lc] = w4.z; WT[(k + 3) * WPAD + lc] = w4.w;
    }
  }
  if (tid < 128) {
    const float4 wo = *(const float4*)&Wout[(size_t)etag * (2 * Hn) + dir * Hn + tid * 4];
    *(float4*)&WoL[tid * 4] = wo;
  }

  // ---- per-thread persistent state ----
  const int pb = tid & 127;
  const int ph = tid >> 7;
  const int hidx = hidx0 + ph;
  const float bi = bias[hidx];
  const float bff = bias[Hn + hidx];
  const float bgg = bias[2 * Hn + hidx];
  const float bo = bias[3 * Hn + hidx];
  float c_reg = 0.f, h_reg = 0.f;

  const int xbq = tid & 127;
  const int xeg = tid >> 7;
  const size_t xrow = (size_t)xbq * (Tn * En);

  // prefetch X chunks 0,1 for s=0
  float4 xA[8];
  {
    const int t0 = dir ? (Tn - 1) : 0;
    #pragma unroll
    for (int r = 0; r < 8; ++r)
      xA[r] = *(const float4*)&X[xrow + (size_t)t0 * En + (r >> 2) * 64 + xeg * 16 + (r & 3) * 4];
  }

  // ================= step loop =================
  #pragma unroll 1
  for (int s = 0; s < Tn; ++s) {
    const int t = dir ? (Tn - 1 - s) : s;
    const float* hprev = hbuf + ((s + 1) & 1) * (Hn * Bn);
    float*       hnext = hbuf + (s & 1) * (Hn * Bn);
    const float mval = masks[(size_t)pb * Tn + t];

    // write chunk 0 (X e 0..63) to HX[0]
    #pragma unroll
    for (int r = 0; r < 4; ++r) {
      const int el = xeg * 16 + r * 4;
      HX[0][(el + 0) * LDW + xbq] = xA[r].x;
      HX[0][(el + 1) * LDW + xbq] = xA[r].y;
      HX[0][(el + 2) * LDW + xbq] = xA[r].z;
      HX[0][(el + 3) * LDW + xbq] = xA[r].w;
    }
    __syncthreads();

    // issue X chunks 2,3 loads
    float4 xB[8];
    #pragma unroll
    for (int r = 0; r < 8; ++r)
      xB[r] = *(const float4*)&X[xrow + (size_t)t * En + 128 + (r >> 2) * 64 + xeg * 16 + (r & 3) * 4];

    float acc[4][8];
    #pragma unroll
    for (int m = 0; m < 4; ++m)
      #pragma unroll
      for (int n = 0; n < 8; ++n) acc[m][n] = 0.f;
    float eacc = 0.f;
    float4 st[4];

    // ---- 12 chunks: c 0..3 = X (Wih rows 512+), c 4..11 = h (Whh rows 0..511) ----
    #pragma unroll 1
    for (int c = 0; c < 12; ++c) {
      const int nxt = c + 1;
      if (nxt >= 4 && nxt < 12) {        // issue h-chunk loads
        const float* src = hprev + (nxt - 4) * (64 * Bn);
        #pragma unroll
        for (int r = 0; r < 4; ++r)
          st[r] = *(const float4*)&src[(r * 512 + tid) * 4];
      }
      if (c == 11 && s < Tn - 1) {       // prefetch next step's X chunks 0,1
        const int tn = dir ? (Tn - 2 - s) : (s + 1);
        #pragma unroll
        for (int r = 0; r < 8; ++r)
          xA[r] = *(const float4*)&X[xrow + (size_t)tn * En + (r >> 2) * 64 + xeg * 16 + (r & 3) * 4];
      }

      // compute chunk c
      {
        const float* HXc = &HX[c & 1][0];
        const int wk0 = (c < 4) ? (512 + c * 64) : ((c - 4) * 64);
        #pragma unroll
        for (int j = 0; j < 8; ++j) {
          const int l = kt * 16 + j * 2 + khalf;
          const float4 av = *(const float4*)&HXc[l * LDW + bg * 4];
          const float4 wa = *(const float4*)&WT[(wk0 + l) * WPAD + cg * 8];
          const float4 wb = *(const float4*)&WT[(wk0 + l) * WPAD + cg * 8 + 4];
          const float avf[4] = {av.x, av.y, av.z, av.w};
          const float wvf[8] = {wa.x, wa.y, wa.z, wa.w, wb.x, wb.y, wb.z, wb.w};
          #pragma unroll
          for (int m = 0; m < 4; ++m)
            #pragma unroll
            for (int n = 0; n < 8; ++n)
              acc[m][n] += avf[m] * wvf[n];
        }
        if (s > 0 && c >= 4) {           // emission partial over hprev panel
          const int be = tid & 31;
          const int kq = tid >> 5;
          #pragma unroll
          for (int j = 0; j < 4; ++j)
            eacc += HXc[(kq * 4 + j) * LDW + ebq * 32 + be] * WoL[(c - 4) * 64 + kq * 4 + j];
        }
      }

      // stage writes for nxt
      if (nxt == 1) {
        #pragma unroll
        for (int r = 0; r < 4; ++r) {
          const int el = xeg * 16 + r * 4;
          HX[1][(el + 0) * LDW + xbq] = xA[4 + r].x;
          HX[1][(el + 1) * LDW + xbq] = xA[4 + r].y;
          HX[1][(el + 2) * LDW + xbq] = xA[4 + r].z;
          HX[1][(el + 3) * LDW + xbq] = xA[4 + r].w;
        }
      } else if (nxt == 2 || nxt == 3) {
        float* dst = &HX[nxt & 1][0];
        const int o = (nxt - 2) * 4;
        #pragma unroll
        for (int r = 0; r < 4; ++r) {
          const int el = xeg * 16 + r * 4;
          dst[(el + 0) * LDW + xbq] = xB[o + r].x;
          dst[(el + 1) * LDW + xbq] = xB[o + r].y;
          dst[(el + 2) * LDW + xbq] = xB[o + r].z;
          dst[(el + 3) * LDW + xbq] = xB[o + r].w;
        }
      } else if (nxt >= 4 && nxt < 12) {
        float* dst = &HX[nxt & 1][0];
        #pragma unroll
        for (int r = 0; r < 4; ++r) {
          const int item = r * 512 + tid;
          *(float4*)&dst[(item >> 5) * LDW + (item & 31) * 4] = st[r];
        }
      }
      __syncthreads();
    }

    // ---- k-split reduction (P overlay on HX) + emission stash ----
    float* P = &HX[0][0];
    const int ks = kt * 2 + khalf;
    #pragma unroll
    for (int n = 0; n < 8; ++n)
      *(float4*)&P[ks * 2048 + (cg * 8 + n) * 128 + bg * 4] =
          make_float4(acc[0][n], acc[1][n], acc[2][n], acc[3][n]);
    RS[(tid >> 5) * 32 + (tid & 31)] = eacc;
    __syncthreads();
    {
      const int b  = tid & 127;
      const int cq = tid >> 7;
      float g4[4] = {0.f, 0.f, 0.f, 0.f};
      #pragma unroll
      for (int k2 = 0; k2 < 8; ++k2)
        #pragma unroll
        for (int ci = 0; ci < 4; ++ci)
          g4[ci] += P[k2 * 2048 + (cq * 4 + ci) * 128 + b];
      #pragma unroll
      for (int ci = 0; ci < 4; ++ci)
        GL[b * 17 + cq * 4 + ci] = g4[ci];
    }
    __syncthreads();

    // ---- pointwise update (state in regs) ----
    {
      const float gi = GL[pb * 17 + ph]       + bi;
      const float gf = GL[pb * 17 + 4 + ph]   + bff;
      const float gc = GL[pb * 17 + 8 + ph]   + bgg;
      const float go = GL[pb * 17 + 12 + ph]  + bo;
      const float iv = 1.f / (1.f + expf(-gi));
      const float fv = 1.f / (1.f + expf(-gf));
      const float gv = tanhf(gc);
      const float ov = 1.f / (1.f + expf(-go));
      const float cnew = fv * c_reg + iv * gv;
      const float hnew = ov * tanhf(cnew);
      if (mval > 0.f) { h_reg = hnew; c_reg = cnew; }
      hnext[hidx * Bn + pb] = h_reg;
    }

    // ---- emission finish for tprev ----
    if (tid < 32 && s > 0) {
      const int tprev = dir ? (Tn - s) : (s - 1);
      float v = 0.f;
      #pragma unroll
      for (int g = 0; g < 16; ++g) v += RS[g * 32 + tid];
      Edst[(size_t)tprev * (NTAGS * Bn) + etag * Bn + ebq * 32 + tid] = v;
    }

    gridbar(bar, blk, tid, (unsigned)(s + 1));
  }
}

__global__ __launch_bounds__(512) void emis_final_k(const float* __restrict__ Wout,
                                                    float* __restrict__ ws)
{
  __shared__ float RSf[16 * Bn];
  const int tid = threadIdx.x;
  const int dir = blockIdx.x >> 5;
  const int tag = blockIdx.x & 31;
  // final states: h_f[T-1] and h_b[0] both written at s=511 (buf 1)
  const float* hsrc = ws + (dir ? OFF_HB : OFF_HF) + 1 * (Hn * Bn);
  const int tprev = dir ? 0 : (Tn - 1);
  const float* wrow = Wout + (size_t)tag * (2 * Hn) + dir * Hn;
  float* Edst = ws + (dir ? OFF_EB : OFF_EF);
  const int bq = tid & 31;
  const int kg = tid >> 5;
  float4 a4 = make_float4(0.f, 0.f, 0.f, 0.f);
  #pragma unroll 4
  for (int kk = 0; kk < 32; ++kk) {
    const int k = kg * 32 + kk;
    const float w = wrow[k];
    const float4 h4 = *(const float4*)&hsrc[k * Bn + bq * 4];
    a4.x += h4.x * w; a4.y += h4.y * w; a4.z += h4.z * w; a4.w += h4.w * w;
  }
  *(float4*)&RSf[kg * Bn + bq * 4] = a4;
  __syncthreads();
  if (tid < 128) {
    float v = 0.f;
    #pragma unroll
    for (int g = 0; g < 16; ++g) v += RSf[g * Bn + tid];
    Edst[(size_t)tprev * (NTAGS * Bn) + tag * Bn + tid] = v;
  }
}

__global__ __launch_bounds__(64) void viterbi_k(
    const float* __restrict__ Ef, const float* __restrict__ Eb,
    const float* __restrict__ bout, const float* __restrict__ trans,
    const float* __restrict__ masks, float* __restrict__ out)
{
  const int b = blockIdx.x;
  const int l = threadIdx.x;
  __shared__ float tr[32][32];
  __shared__ float al[32];
  __shared__ float msk[512];
  __shared__ unsigned char bp[512][32];
  __shared__ int tseq[512];

  for (int i = l; i < 1024; i += 64) tr[i >> 5][i & 31] = trans[i];
  for (int i = l; i < 512; i += 64) msk[i] = masks[(size_t)b * 512 + i];
  __syncthreads();

  const int j  = l & 31;
  const int hi = l >> 5;
  if (l < 32)
    al[j] = Ef[(size_t)j * Bn + b] + Eb[(size_t)j * Bn + b] + bout[j] + tr[30][j];
  __syncthreads();

  for (int t = 1; t < 512; ++t) {
    float pmax = -FLT_MAX; int pidx = 0;
    #pragma unroll
    for (int ii = 0; ii < 16; ++ii) {
      const int i = hi * 16 + ii;
      const float sc = al[i] + tr[i][j];
      if (sc > pmax) { pmax = sc; pidx = i; }   // strict > => first occurrence
    }
    const float omax = __shfl_down(pmax, 32);
    const int   oidx = __shfl_down(pidx, 32);
    if (l < 32) {
      if (omax > pmax) { pmax = omax; pidx = oidx; } // high half only on strict >
      bp[t][j] = (unsigned char)pidx;
      const float e = Ef[(size_t)t * (NTAGS * Bn) + j * Bn + b]
                    + Eb[(size_t)t * (NTAGS * Bn) + j * Bn + b] + bout[j];
      const float na = pmax + e;
      if (msk[t] > 0.f) al[j] = na;
    }
    __syncthreads();
  }

  float fv; int fidx;
  if (l < 32) { fv = al[l] + tr[l][31]; fidx = l; }
  else        { fv = -FLT_MAX; fidx = 1 << 30; }
  #pragma unroll
  for (int off = 16; off >= 1; off >>= 1) {
    const float v2 = __shfl_xor(fv, off);
    const int   i2 = __shfl_xor(fidx, off);
    if (v2 > fv || (v2 == fv && i2 < fidx)) { fv = v2; fidx = i2; }
  }
  if (l == 0) {
    out[b] = fv;
    int cur = fidx;
    tseq[511] = cur;
    for (int t = 511; t >= 1; --t) {
      const int prev = (msk[t] > 0.f) ? (int)bp[t][cur] : cur;
      tseq[t - 1] = prev;
      cur = prev;
    }
  }
  __syncthreads();
  for (int t = l; t < 512; t += 64) {
    const float tv = (msk[t] > 0.f) ? (float)tseq[t] : -1.0f;
    out[Bn + (size_t)b * 512 + t] = tv;
  }
}

extern "C" void kernel_launch(void* const* d_in, const int* in_sizes, int n_in,
                              void* d_out, int out_size, void* d_ws, size_t ws_size,
                              hipStream_t stream) {
  const float* X      = (const float*)d_in[0];
  const float* masks  = (const float*)d_in[1];
  const float* Wih_f  = (const float*)d_in[3];
  const float* Whh_f  = (const float*)d_in[4];
  const float* bf     = (const float*)d_in[5];
  const float* Wih_b  = (const float*)d_in[6];
  const float* Whh_b  = (const float*)d_in[7];
  const float* bb     = (const float*)d_in[8];
  const float* Wout   = (const float*)d_in[9];
  const float* bout   = (const float*)d_in[10];
  const float* trans  = (const float*)d_in[11];
  float* ws  = (float*)d_ws;
  float* out = (float*)d_out;

  // zero h buffers + barrier state (graph replays re-run this)
  hipMemsetAsync(d_ws, 0, (size_t)OFF_EF * sizeof(float), stream);

  lstm_persist_k<<<256, 512, 0, stream>>>(X, masks, Wih_f, Whh_f, bf,
                                          Wih_b, Whh_b, bb, Wout, ws);
  emis_final_k<<<64, 512, 0, stream>>>(Wout, ws);
  viterbi_k<<<128, 64, 0, stream>>>(ws + OFF_EF, ws + OFF_EB, bout, trans, masks, out);
}

// Round 7
// 11282.745 us; speedup vs baseline: 2.5776x; 2.5776x over previous
//
#include <hip/hip_runtime.h>
#include <cfloat>
#include <cmath>

#define Bn 128
#define Tn 512
#define En 256
#define Hn 512
#define NTAGS 32
#define CHK 64                   // k-rows per staged chunk
#define NCHK 12                  // 8 h-chunks (512 k) + 4 x-chunks (256 k)

// ws float offsets (h stored [k][b] dense)
#define OFF_HF 0                          // [2][512][128]
#define OFF_HB 131072
#define OFF_CF 262144                     // [512][128]
#define OFF_CB 327680
#define OFF_EF 393216                     // [512][32][128]
#define OFF_EB 2490368
// end 4587520 floats = 17.5 MB

__device__ __forceinline__ void gll16(const float* g, float* l) {
  __builtin_amdgcn_global_load_lds(
      (const __attribute__((address_space(1))) void*)g,
      (__attribute__((address_space(3))) void*)l, 16, 0, 0);
}

__global__ __launch_bounds__(512, 2) void lstm_step_k(
    const float* __restrict__ X, const float* __restrict__ masks,
    const float* __restrict__ Wih_f, const float* __restrict__ Whh_f, const float* __restrict__ bias_f,
    const float* __restrict__ Wih_b, const float* __restrict__ Whh_b, const float* __restrict__ bias_b,
    const float* __restrict__ Wout, float* __restrict__ ws, int s)
{
  __shared__ __align__(16) float WT[768 * 16];      // 49 KB  W [k][c] (reads are uniform broadcasts)
  __shared__ __align__(16) float HX[2][CHK * Bn];   // 65.5 KB A chunks [k][b] dense (gll16 linear dest)
  __shared__ __align__(16) float GL[Bn * 17];       // 8.7 KB gates [b][c]
  __shared__ __align__(16) float WoL[512];          // 2 KB   Wout row (block's tag/dir)
  __shared__ __align__(16) float RS[16 * 32];       // 2 KB   emission partials

  const int tid   = threadIdx.x;
  const int blk   = blockIdx.x;
  const int lane  = tid & 63;
  const int wid   = __builtin_amdgcn_readfirstlane(tid >> 6);  // 0..7 uniform
  const int cg    = wid & 1;    // c half: cols [cg*8, cg*8+8)
  const int kt    = wid >> 1;   // k quarter of chunk: [kt*16, +16)
  const int bg    = lane & 31;  // b quad: [bg*4, +4)
  const int khalf = lane >> 5;  // k parity within pair

  const int dir = blk >> 7;
  const int bbk = blk & 127;
  const int t = dir ? (Tn - 1 - s) : s;
  const float* Wih  = dir ? Wih_b  : Wih_f;
  const float* Whh  = dir ? Whh_b  : Whh_f;
  const float* bias = dir ? bias_b : bias_f;
  float* hbuf = ws + (dir ? OFF_HB : OFF_HF);
  float* cbuf = ws + (dir ? OFF_CB : OFF_CF);
  const int rbuf = (s + 1) & 1;
  const int wbuf = s & 1;
  const float* hprev = hbuf + rbuf * (Hn * Bn);
  float*       hnext = hbuf + wbuf * (Hn * Bn);
  const int hidx0 = bbk * 4;

  // emission role: (dir, tag, 32-wide b slice)
  const int etag = bbk & 31;
  const int ebq  = bbk >> 5;

  // ---- prologue: issue chunk-0 staging (gll16), then stage W + WoL ----
  #pragma unroll
  for (int r = 0; r < 4; ++r) {
    const int item = r * 512 + tid;                // 2048 float4 = 64x128
    gll16(hprev + item * 4, &HX[0][item * 4]);
  }
  {
    const int lc = tid & 15;
    const int kw = tid >> 4;                       // 0..31
    const int row = (lc >> 2) * Hn + hidx0 + (lc & 3);
    #pragma unroll
    for (int i = 0; i < 6; ++i) {
      const int k = (kw + i * 32) * 4;             // 0..764
      float4 w4;
      if (k < Hn) w4 = *(const float4*)&Whh[(size_t)row * Hn + k];
      else        w4 = *(const float4*)&Wih[(size_t)row * En + (k - Hn)];
      WT[(k + 0) * 16 + lc] = w4.x; WT[(k + 1) * 16 + lc] = w4.y;
      WT[(k + 2) * 16 + lc] = w4.z; WT[(k + 3) * 16 + lc] = w4.w;
    }
  }
  if (tid < 128) {
    const float4 wo = *(const float4*)&Wout[(size_t)etag * (2 * Hn) + dir * Hn + tid * 4];
    *(float4*)&WoL[tid * 4] = wo;
  }
  __syncthreads();

  float acc[4][8];
  #pragma unroll
  for (int m = 0; m < 4; ++m)
    #pragma unroll
    for (int n = 0; n < 8; ++n) acc[m][n] = 0.f;
  float eacc = 0.f;

  const int xbq = tid & 127;                       // for x staging
  const int xeg = tid >> 7;                        // 0..3

  // ---- main loop: 12 chunks of 64 k (c 0..7 = h via gll16, c 8..11 = x via regs) ----
  #pragma unroll 1
  for (int c = 0; c < NCHK; ++c) {
    const int nxt = c + 1;
    float4 st[4];
    if (nxt < 8) {
      // stage next h-chunk via global_load_lds (fire and forget; barrier drains)
      const float* src = hprev + nxt * (CHK * Bn);
      float* dst = &HX[nxt & 1][0];
      #pragma unroll
      for (int r = 0; r < 4; ++r) {
        const int item = r * 512 + tid;
        gll16(src + item * 4, dst + item * 4);
      }
    } else if (nxt < NCHK) {
      const int e0 = (nxt - 8) * CHK;
      #pragma unroll
      for (int r = 0; r < 4; ++r)
        st[r] = *(const float4*)&X[(size_t)xbq * (Tn * En) + (size_t)t * En + e0 + xeg * 16 + r * 4];
    }

    // ---- compute chunk c ----
    {
      const float* HXc = &HX[c & 1][0];
      #pragma unroll
      for (int j = 0; j < 8; ++j) {
        const int l = kt * 16 + j * 2 + khalf;     // local k
        const float4 av = *(const float4*)&HXc[l * Bn + bg * 4];
        const float4 wa = *(const float4*)&WT[(c * 64 + l) * 16 + cg * 8];
        const float4 wb = *(const float4*)&WT[(c * 64 + l) * 16 + cg * 8 + 4];
        const float avf[4] = {av.x, av.y, av.z, av.w};
        const float wvf[8] = {wa.x, wa.y, wa.z, wa.w, wb.x, wb.y, wb.z, wb.w};
        #pragma unroll
        for (int m = 0; m < 4; ++m)
          #pragma unroll
          for (int n = 0; n < 8; ++n)
            acc[m][n] += avf[m] * wvf[n];
      }
      // emission partial from same panel (h-chunks only)
      if (c < 8) {
        const int be = tid & 31;
        const int kq = tid >> 5;                   // 0..15
        #pragma unroll
        for (int j = 0; j < 4; ++j)
          eacc += HXc[(kq * 4 + j) * Bn + ebq * 32 + be] * WoL[c * 64 + kq * 4 + j];
      }
    }

    // ---- write staged x regs into next buffer ----
    if (nxt >= 8 && nxt < NCHK) {
      float* dst = &HX[nxt & 1][0];
      #pragma unroll
      for (int r = 0; r < 4; ++r) {
        const int el = xeg * 16 + r * 4;
        dst[(el + 0) * Bn + xbq] = st[r].x;
        dst[(el + 1) * Bn + xbq] = st[r].y;
        dst[(el + 2) * Bn + xbq] = st[r].z;
        dst[(el + 3) * Bn + xbq] = st[r].w;
      }
    }
    __syncthreads();
  }

  // ---- k-split reduction: P[ks=kt*2+khalf][c16][b128] overlaid on HX ----
  float* P = &HX[0][0];                            // 16384 floats
  const int ks = kt * 2 + khalf;
  #pragma unroll
  for (int n = 0; n < 8; ++n)
    *(float4*)&P[ks * 2048 + (cg * 8 + n) * 128 + bg * 4] =
        make_float4(acc[0][n], acc[1][n], acc[2][n], acc[3][n]);
  RS[(tid >> 5) * 32 + (tid & 31)] = eacc;
  __syncthreads();
  {
    const int b  = tid & 127;
    const int cq = tid >> 7;                       // 0..3
    float g4[4] = {0.f, 0.f, 0.f, 0.f};
    #pragma unroll
    for (int k2 = 0; k2 < 8; ++k2)
      #pragma unroll
      for (int ci = 0; ci < 4; ++ci)
        g4[ci] += P[k2 * 2048 + (cq * 4 + ci) * 128 + b];
    #pragma unroll
    for (int ci = 0; ci < 4; ++ci)
      GL[b * 17 + cq * 4 + ci] = g4[ci];
  }
  __syncthreads();

  // ---- LSTM pointwise update ----
  {
    const int b  = tid & 127;
    const int hh = tid >> 7;
    const int hidx = hidx0 + hh;
    const float gi = GL[b * 17 + hh]      + bias[hidx];
    const float gf = GL[b * 17 + 4 + hh]  + bias[Hn + hidx];
    const float gc = GL[b * 17 + 8 + hh]  + bias[2 * Hn + hidx];
    const float go = GL[b * 17 + 12 + hh] + bias[3 * Hn + hidx];
    const float iv = 1.f / (1.f + expf(-gi));
    const float fv = 1.f / (1.f + expf(-gf));
    const float gv = tanhf(gc);
    const float ov = 1.f / (1.f + expf(-go));
    const float cold = cbuf[hidx * Bn + b];
    const float cnew = fv * cold + iv * gv;
    const float hold = hprev[hidx * Bn + b];
    const float hnew = ov * tanhf(cnew);
    const float m = masks[(size_t)b * Tn + t];
    hnext[hidx * Bn + b] = (m > 0.f) ? hnew : hold;
    cbuf[hidx * Bn + b]  = (m > 0.f) ? cnew : cold;
  }

  // ---- emission finish: E_dir[tprev][etag][ebq slice] ----
  if (tid < 32 && s > 0) {
    const int tprev = dir ? (Tn - s) : (s - 1);
    float* Edst = ws + (dir ? OFF_EB : OFF_EF);
    float v = 0.f;
    #pragma unroll
    for (int g = 0; g < 16; ++g) v += RS[g * 32 + tid];
    Edst[(size_t)tprev * (NTAGS * Bn) + etag * Bn + ebq * 32 + tid] = v;
  }
}

__global__ __launch_bounds__(512) void emis_final_k(const float* __restrict__ Wout,
                                                    float* __restrict__ ws)
{
  __shared__ float RSf[16 * Bn];
  const int tid = threadIdx.x;
  const int dir = blockIdx.x >> 5;
  const int tag = blockIdx.x & 31;
  // final states: h_f[T-1] and h_b[0] both written at s=511 (wbuf=1)
  const float* hsrc = ws + (dir ? OFF_HB : OFF_HF) + 1 * (Hn * Bn);
  const int tprev = dir ? 0 : (Tn - 1);
  const float* wrow = Wout + (size_t)tag * (2 * Hn) + dir * Hn;
  float* Edst = ws + (dir ? OFF_EB : OFF_EF);
  const int bq = tid & 31;
  const int kg = tid >> 5;
  float4 a4 = make_float4(0.f, 0.f, 0.f, 0.f);
  #pragma unroll 4
  for (int kk = 0; kk < 32; ++kk) {
    const int k = kg * 32 + kk;
    const float w = wrow[k];
    const float4 h4 = *(const float4*)&hsrc[k * Bn + bq * 4];
    a4.x += h4.x * w; a4.y += h4.y * w; a4.z += h4.z * w; a4.w += h4.w * w;
  }
  *(float4*)&RSf[kg * Bn + bq * 4] = a4;
  __syncthreads();
  if (tid < 128) {
    float v = 0.f;
    #pragma unroll
    for (int g = 0; g < 16; ++g) v += RSf[g * Bn + tid];
    Edst[(size_t)tprev * (NTAGS * Bn) + tag * Bn + tid] = v;
  }
}

__global__ __launch_bounds__(64) void viterbi_k(
    const float* __restrict__ Ef, const float* __restrict__ Eb,
    const float* __restrict__ bout, const float* __restrict__ trans,
    const float* __restrict__ masks, float* __restrict__ out)
{
  const int b = blockIdx.x;
  const int l = threadIdx.x;
  __shared__ float tr[32][32];
  __shared__ float al[32];
  __shared__ float msk[512];
  __shared__ unsigned char bp[512][32];
  __shared__ int tseq[512];

  for (int i = l; i < 1024; i += 64) tr[i >> 5][i & 31] = trans[i];
  for (int i = l; i < 512; i += 64) msk[i] = masks[(size_t)b * 512 + i];
  __syncthreads();

  const int j  = l & 31;
  const int hi = l >> 5;
  if (l < 32)
    al[j] = Ef[(size_t)j * Bn + b] + Eb[(size_t)j * Bn + b] + bout[j] + tr[30][j];
  __syncthreads();

  for (int t = 1; t < 512; ++t) {
    float pmax = -FLT_MAX; int pidx = 0;
    #pragma unroll
    for (int ii = 0; ii < 16; ++ii) {
      const int i = hi * 16 + ii;
      const float sc = al[i] + tr[i][j];
      if (sc > pmax) { pmax = sc; pidx = i; }   // strict > => first occurrence
    }
    const float omax = __shfl_down(pmax, 32);
    const int   oidx = __shfl_down(pidx, 32);
    if (l < 32) {
      if (omax > pmax) { pmax = omax; pidx = oidx; } // high half only on strict >
      bp[t][j] = (unsigned char)pidx;
      const float e = Ef[(size_t)t * (NTAGS * Bn) + j * Bn + b]
                    + Eb[(size_t)t * (NTAGS * Bn) + j * Bn + b] + bout[j];
      const float na = pmax + e;
      if (msk[t] > 0.f) al[j] = na;
    }
    __syncthreads();
  }

  float fv; int fidx;
  if (l < 32) { fv = al[l] + tr[l][31]; fidx = l; }
  else        { fv = -FLT_MAX; fidx = 1 << 30; }
  #pragma unroll
  for (int off = 16; off >= 1; off >>= 1) {
    const float v2 = __shfl_xor(fv, off);
    const int   i2 = __shfl_xor(fidx, off);
    if (v2 > fv || (v2 == fv && i2 < fidx)) { fv = v2; fidx = i2; }
  }
  if (l == 0) {
    out[b] = fv;
    int cur = fidx;
    tseq[511] = cur;
    for (int t = 511; t >= 1; --t) {
      const int prev = (msk[t] > 0.f) ? (int)bp[t][cur] : cur;
      tseq[t - 1] = prev;
      cur = prev;
    }
  }
  __syncthreads();
  for (int t = l; t < 512; t += 64) {
    const float tv = (msk[t] > 0.f) ? (float)tseq[t] : -1.0f;
    out[Bn + (size_t)b * 512 + t] = tv;
  }
}

extern "C" void kernel_launch(void* const* d_in, const int* in_sizes, int n_in,
                              void* d_out, int out_size, void* d_ws, size_t ws_size,
                              hipStream_t stream) {
  const float* X      = (const float*)d_in[0];
  const float* masks  = (const float*)d_in[1];
  const float* Wih_f  = (const float*)d_in[3];
  const float* Whh_f  = (const float*)d_in[4];
  const float* bf     = (const float*)d_in[5];
  const float* Wih_b  = (const float*)d_in[6];
  const float* Whh_b  = (const float*)d_in[7];
  const float* bb     = (const float*)d_in[8];
  const float* Wout   = (const float*)d_in[9];
  const float* bout   = (const float*)d_in[10];
  const float* trans  = (const float*)d_in[11];
  float* ws  = (float*)d_ws;
  float* out = (float*)d_out;

  // zero h/c state region (graph replays re-run this)
  hipMemsetAsync(d_ws, 0, (size_t)OFF_EF * sizeof(float), stream);

  for (int s = 0; s < Tn; ++s)
    lstm_step_k<<<256, 512, 0, stream>>>(X, masks, Wih_f, Whh_f, bf,
                                         Wih_b, Whh_b, bb, Wout, ws, s);
  emis_final_k<<<64, 512, 0, stream>>>(Wout, ws);
  viterbi_k<<<128, 64, 0, stream>>>(ws + OFF_EF, ws + OFF_EB, bout, trans, masks, out);
}